// Round 2
// baseline (93.079 us; speedup 1.0000x reference)
//
#include <hip/hip_runtime.h>
#include <math.h>

// GMM score, rescaled: out_j = (E_w[td] - x_j) / sigma2_j
// w_i = exp(-0.5 (td_i - x_j)^2 / sigma2_j), sigma2_j = (exp(2 t_j ln25)-1)/(2 ln25)
//
// Timing model (R1 revision): dur = ~41us harness ws-poison (fixed, 256MiB fill
//   at 83% HBM peak) + gmm_partial + gmm_final + gaps.
// R1 re-derivation: v_exp_f32 is QUARTER-rate on SIMD-32 => 8 cyc/wave-instr
// (not 16 as the old fitted model assumed). Serial-issue floor per v2f bundle:
// 4 pk-VALU @2cyc + 2 exp @8cyc = 24 cyc -> 20.5us; trans-pipe floor 13.7us.
// Measured 40us is ~2x floor => theory: overhead/latency-bound (block prologue,
// ds_read+loop issue slots, exp dep chains), NOT trans-pipe-bound.
// R1 experiment: 2 outputs per thread (j, j+256). Amortizes LDS reads, loop
// overhead, and block prologue over 2x evals; doubles in-wave ILP for exp
// chains. Trans work per element unchanged. Grid 2048 -> 1024 blocks.
// Prediction: partial 40 -> 33-36us if theory right (total ~86-89us);
// unchanged if trans-bound at 16cyc (then structure is at roofline).

typedef float v2f __attribute__((ext_vector_type(2)));

#define BLK   256
#define JPT   2      // outputs per thread
#define CH    512    // train elements per slice (2 KB LDS); S = N/CH = 32

#if __has_builtin(__builtin_amdgcn_exp2f)
#define EXP2(x) __builtin_amdgcn_exp2f(x)
#else
#define EXP2(x) exp2f(x)
#endif

__device__ __forceinline__ float sigma2_of(float tj) {
  const float TWO_LOG_S = 6.4377516497364011f;   // 2*ln(25)
  return (__expf(TWO_LOG_S * tj) - 1.0f) / TWO_LOG_S;
}

template <bool ATOMIC>
__launch_bounds__(BLK, 4)
__global__ void gmm_partial(const float* __restrict__ x,
                            const float* __restrict__ t,
                            const float* __restrict__ td,
                            float* __restrict__ ws,
                            int N, int B) {
  __shared__ float lds[CH];
  const int tid  = threadIdx.x;
  const int j0   = blockIdx.x * (BLK * JPT) + tid;   // first output index
  const int j1   = j0 + BLK;                          // second output index
  const int s    = blockIdx.y;                        // N-slice
  const int S    = gridDim.y;
  const int base = s * CH;

  for (int i = tid; i < CH; i += BLK) {
    int gi = base + i;
    // pad -> d^2 = inf -> exp2(-inf) = 0 (weightless)
    lds[i] = (gi < N) ? td[gi] : 1e30f;
  }

  const float HALF_LOG2E = 0.72134752044448170f;  // 0.5 * log2(e)
  float r0 = 0.0f, y0 = 0.0f, r1 = 0.0f, y1 = 0.0f;
  if (j0 < B) {
    float s2 = sigma2_of(t[j0]);
    r0 = __fsqrt_rn(HALF_LOG2E / s2);   // d = (td - x)*r ; arg = -d^2
    y0 = x[j0] * r0;
  }
  if (j1 < B) {
    float s2 = sigma2_of(t[j1]);
    r1 = __fsqrt_rn(HALF_LOG2E / s2);
    y1 = x[j1] * r1;
  }
  __syncthreads();

  const v2f rv0  = {r0, r0};
  const v2f nyv0 = {-y0, -y0};
  const v2f rv1  = {r1, r1};
  const v2f nyv1 = {-y1, -y1};

  // per-j accumulators: 2 num + 2 den (v2f) each
  v2f n00 = {0.f, 0.f}, n01 = {0.f, 0.f}, d00 = {0.f, 0.f}, d01 = {0.f, 0.f};
  v2f n10 = {0.f, 0.f}, n11 = {0.f, 0.f}, d10 = {0.f, 0.f}, d11 = {0.f, 0.f};

  const float4* l4 = (const float4*)lds;   // ds_read_b128 broadcast, conflict-free
  const int iters = CH >> 3;               // 8 td elements per iteration

#define GROUP(v, naccA, daccA, naccB, daccB)                            \
  {                                                                     \
    v2f dA = __builtin_elementwise_fma(v, rv0, nyv0);                   \
    v2f dB = __builtin_elementwise_fma(v, rv1, nyv1);                   \
    v2f qA = dA * dA;                                                   \
    v2f qB = dB * dB;                                                   \
    v2f pA, pB;                                                         \
    pA.x = EXP2(-qA.x); pA.y = EXP2(-qA.y);                             \
    pB.x = EXP2(-qB.x); pB.y = EXP2(-qB.y);                             \
    daccA += pA;                                                        \
    daccB += pB;                                                        \
    naccA = __builtin_elementwise_fma(pA, v, naccA);                    \
    naccB = __builtin_elementwise_fma(pB, v, naccB);                    \
  }

  #pragma unroll 2
  for (int i = 0; i < iters; ++i) {
    float4 v0 = l4[2 * i];
    float4 v1 = l4[2 * i + 1];
    v2f va = {v0.x, v0.y}, vb = {v0.z, v0.w};
    v2f vc = {v1.x, v1.y}, vd = {v1.z, v1.w};
    GROUP(va, n00, d00, n10, d10)
    GROUP(vb, n01, d01, n11, d11)
    GROUP(vc, n00, d00, n10, d10)
    GROUP(vd, n01, d01, n11, d11)
  }
#undef GROUP

  v2f numv0 = n00 + n01, denv0 = d00 + d01;
  v2f numv1 = n10 + n11, denv1 = d10 + d11;
  float num0 = numv0.x + numv0.y, den0 = denv0.x + denv0.y;
  float num1 = numv1.x + numv1.y, den1 = denv1.x + denv1.y;

  if (j0 < B) {
    if (ATOMIC) {
      atomicAdd(&ws[j0], num0);
      atomicAdd(&ws[B + j0], den0);
    } else {
      ws[(size_t)s * B + j0]       = num0;   // num partials: [S][B]
      ws[(size_t)(S + s) * B + j0] = den0;   // den partials: [S][B]
    }
  }
  if (j1 < B) {
    if (ATOMIC) {
      atomicAdd(&ws[j1], num1);
      atomicAdd(&ws[B + j1], den1);
    } else {
      ws[(size_t)s * B + j1]       = num1;
      ws[(size_t)(S + s) * B + j1] = den1;
    }
  }
}

// Parallel final reduction: block = 32 j's x 8 slice-groups; each thread sums
// slices s = g, g+8, g+16, ... (coalesced across the 32 j-lanes), then LDS
// combine over the 8 groups and epilogue. Grid = ceil(B/32) blocks.
#define FJ 32   // j's per final block
#define FG 8    // slice-groups per final block
__launch_bounds__(FJ * FG)
__global__ void gmm_final(const float* __restrict__ x,
                          const float* __restrict__ t,
                          const float* __restrict__ ws,
                          float* __restrict__ out, int B, int S) {
  __shared__ float nbuf[FG * FJ];
  __shared__ float dbuf[FG * FJ];
  const int tid = threadIdx.x;
  const int jl  = tid & (FJ - 1);     // j lane
  const int g   = tid >> 5;           // slice group
  const int j   = blockIdx.x * FJ + jl;

  float np = 0.f, dp = 0.f;
  if (j < B) {
    for (int s = g; s < S; s += FG) {
      np += ws[(size_t)s * B + j];
      dp += ws[(size_t)(S + s) * B + j];
    }
  }
  nbuf[tid] = np;
  dbuf[tid] = dp;
  __syncthreads();

  if (g == 0 && j < B) {
    float num = 0.f, den = 0.f;
    #pragma unroll
    for (int gg = 0; gg < FG; ++gg) {
      num += nbuf[gg * FJ + jl];
      den += dbuf[gg * FJ + jl];
    }
    float sigma2 = sigma2_of(t[j]);
    float evals = (den == 0.0f) ? 0.0f : (num / den);   // reference's den==0 guard
    out[j] = (evals - x[j]) / sigma2;
  }
}

__global__ void gmm_final_serial(const float* __restrict__ x,
                                 const float* __restrict__ t,
                                 const float* __restrict__ ws,
                                 float* __restrict__ out, int B, int S) {
  int j = blockIdx.x * blockDim.x + threadIdx.x;
  if (j >= B) return;
  float num = 0.f, den = 0.f;
  for (int s = 0; s < S; ++s) {
    num += ws[(size_t)s * B + j];
    den += ws[(size_t)(S + s) * B + j];
  }
  float sigma2 = sigma2_of(t[j]);
  float evals = (den == 0.0f) ? 0.0f : (num / den);
  out[j] = (evals - x[j]) / sigma2;
}

__global__ void zero_kernel(float* __restrict__ p, int n) {
  int i = blockIdx.x * blockDim.x + threadIdx.x;
  if (i < n) p[i] = 0.0f;
}

extern "C" void kernel_launch(void* const* d_in, const int* in_sizes, int n_in,
                              void* d_out, int out_size, void* d_ws, size_t ws_size,
                              hipStream_t stream) {
  const float* x  = (const float*)d_in[0];
  const float* t  = (const float*)d_in[1];
  const float* td = (const float*)d_in[2];
  float* out = (float*)d_out;
  float* ws  = (float*)d_ws;

  const int B = in_sizes[0];
  const int N = in_sizes[2];

  const int S = (N + CH - 1) / CH;                  // 32 for N=16384
  size_t need = (size_t)2 * S * B * sizeof(float);  // 4 MB

  const int JBLK = BLK * JPT;                       // outputs per block = 512

  if (ws_size >= need) {
    dim3 grid((B + JBLK - 1) / JBLK, S);            // (32, 32) = 1024 blocks
    gmm_partial<false><<<grid, BLK, 0, stream>>>(x, t, td, ws, N, B);
    gmm_final<<<(B + FJ - 1) / FJ, FJ * FG, 0, stream>>>(x, t, ws, out, B, S);
  } else {
    // Fallback: zero + atomic accumulate + serial final (3 dispatches)
    int nzero = 2 * B;
    zero_kernel<<<(nzero + 255) / 256, 256, 0, stream>>>(ws, nzero);
    dim3 grid((B + JBLK - 1) / JBLK, S);
    gmm_partial<true><<<grid, BLK, 0, stream>>>(x, t, td, ws, N, B);
    gmm_final_serial<<<(B + 255) / 256, 256, 0, stream>>>(x, t, ws, out, B, 1);
  }
}